// Round 1
// baseline (1495.462 us; speedup 1.0000x reference)
//
#include <hip/hip_runtime.h>
#include <math.h>

// SOM2dLayer forward: BMU indices + quantization error.
// X[4096,64] f32, W[256*256,64] f32.
// out (float32): [B*2] interleaved (y,x) as floats, then [B] qe.
//
// Strategy: d2' = w2[n] - 2*x.w  (x2 dropped from argmin, added back at the end).
// Each thread owns one batch row (x[64] in VGPRs, statically indexed).
// All threads in a block walk the same n -> w[n][*] and w2[n] are wave-uniform
// -> scalar loads (SGPR broadcast), inner loop = 64 v_fmac with SGPR src.
// N split into STRIPS strips for occupancy; merge kernel does final argmin.

constexpr int D        = 64;
constexpr int NW       = 65536;   // 256*256 weights
constexpr int B        = 4096;
constexpr int W_GRID   = 256;
constexpr int STRIPS   = 32;
constexpr int NSTRIP   = NW / STRIPS;   // 2048
constexpr int ROWBLOCKS = 16;           // 4096 rows / 256 rows-per-block

__global__ __launch_bounds__(256) void w2_kernel(const float* __restrict__ w,
                                                 float* __restrict__ w2) {
    int n = blockIdx.x * 256 + threadIdx.x;
    const float4* wr = reinterpret_cast<const float4*>(w + (size_t)n * D);
    float a0 = 0.f, a1 = 0.f, a2 = 0.f, a3 = 0.f;
#pragma unroll
    for (int q = 0; q < D / 4; ++q) {
        float4 v = wr[q];
        a0 = fmaf(v.x, v.x, a0);
        a1 = fmaf(v.y, v.y, a1);
        a2 = fmaf(v.z, v.z, a2);
        a3 = fmaf(v.w, v.w, a3);
    }
    w2[n] = (a0 + a1) + (a2 + a3);
}

__global__ __launch_bounds__(256) void som_main(const float* __restrict__ x,
                                                const float* __restrict__ w,
                                                const float* __restrict__ w2,
                                                float* __restrict__ ps,
                                                int* __restrict__ pi) {
    const int rb    = blockIdx.x & (ROWBLOCKS - 1);
    const int strip = blockIdx.x >> 4;
    const int row   = rb * 256 + threadIdx.x;

    // Load this row's x into registers (statically indexed -> stays in VGPRs).
    float xr[D];
    const float4* xrow = reinterpret_cast<const float4*>(x + (size_t)row * D);
#pragma unroll
    for (int q = 0; q < D / 4; ++q) {
        float4 v = xrow[q];
        xr[q * 4 + 0] = v.x;
        xr[q * 4 + 1] = v.y;
        xr[q * 4 + 2] = v.z;
        xr[q * 4 + 3] = v.w;
    }

    float best = 3.4e38f;
    int   bidx = 0;
    const int n0 = strip * NSTRIP;
    const int n1 = n0 + NSTRIP;
    for (int n = n0; n < n1; ++n) {
        const float* __restrict__ wr = w + (size_t)n * D;  // wave-uniform -> s_load
        float a0 = 0.f, a1 = 0.f, a2 = 0.f, a3 = 0.f;
#pragma unroll
        for (int d = 0; d < D; d += 4) {
            a0 = fmaf(xr[d + 0], wr[d + 0], a0);
            a1 = fmaf(xr[d + 1], wr[d + 1], a1);
            a2 = fmaf(xr[d + 2], wr[d + 2], a2);
            a3 = fmaf(xr[d + 3], wr[d + 3], a3);
        }
        float s = fmaf(-2.f, (a0 + a1) + (a2 + a3), w2[n]);
        // strict < with ascending n == first-occurrence argmin (matches jnp)
        if (s < best) { best = s; bidx = n; }
    }
    ps[(size_t)strip * B + row] = best;
    pi[(size_t)strip * B + row] = bidx;
}

__global__ __launch_bounds__(256) void som_merge(const float* __restrict__ x,
                                                 const float* __restrict__ ps,
                                                 const int* __restrict__ pi,
                                                 float* __restrict__ out) {
    int row = blockIdx.x * 256 + threadIdx.x;
    float bs = 3.5e38f;
    int   bi = 0;
    // strips visited in ascending-n order -> strict < keeps first occurrence
    for (int t = 0; t < STRIPS; ++t) {
        float s = ps[(size_t)t * B + row];
        int   i = pi[(size_t)t * B + row];
        if (s < bs || (s == bs && i < bi)) { bs = s; bi = i; }
    }
    const float4* xrow = reinterpret_cast<const float4*>(x + (size_t)row * D);
    float a0 = 0.f, a1 = 0.f, a2 = 0.f, a3 = 0.f;
#pragma unroll
    for (int q = 0; q < D / 4; ++q) {
        float4 v = xrow[q];
        a0 = fmaf(v.x, v.x, a0);
        a1 = fmaf(v.y, v.y, a1);
        a2 = fmaf(v.z, v.z, a2);
        a3 = fmaf(v.w, v.w, a3);
    }
    float x2 = (a0 + a1) + (a2 + a3);
    float d2 = x2 + bs;
    d2 = d2 < 0.f ? 0.f : d2;
    out[row * 2 + 0] = (float)(bi >> 8);           // bmu_y = n / 256
    out[row * 2 + 1] = (float)(bi & (W_GRID - 1)); // bmu_x = n % 256
    out[2 * B + row] = sqrtf(d2);
}

extern "C" void kernel_launch(void* const* d_in, const int* in_sizes, int n_in,
                              void* d_out, int out_size, void* d_ws, size_t ws_size,
                              hipStream_t stream) {
    const float* x = (const float*)d_in[0];   // [B, D]
    const float* w = (const float*)d_in[1];   // [H, W, D] = [NW, D]
    float* out = (float*)d_out;               // [B*2 + B] floats

    // workspace layout: w2[NW] | ps[STRIPS*B] | pi[STRIPS*B]  (~1.25 MB)
    float* w2 = (float*)d_ws;
    float* ps = w2 + NW;
    int*   pi = (int*)(ps + (size_t)STRIPS * B);

    w2_kernel<<<NW / 256, 256, 0, stream>>>(w, w2);
    som_main<<<ROWBLOCKS * STRIPS, 256, 0, stream>>>(x, w, w2, ps, pi);
    som_merge<<<B / 256, 256, 0, stream>>>(x, ps, pi, out);
}

// Round 2
// 722.692 us; speedup vs baseline: 2.0693x; 2.0693x over previous
//
#include <hip/hip_runtime.h>
#include <math.h>

// SOM2dLayer forward: BMU indices + quantization error.
// X[4096,64] f32, W[256*256,64] f32.
// out (float32): [B*2] interleaved (y,x) as floats, then [B] qe.
//
// d2' = w2[n] - 2*x.w  (x2 added back in merge). Each thread owns one batch
// row; x is pre-scaled by -2 and PINNED in VGPRs via empty-asm keep-alive
// (round-1 failure: compiler reloaded x inside the n-loop, VGPR=44,
// VALUBusy=18%). All lanes walk the same n -> w row is wave-uniform ->
// s_load into SGPRs. Inner loop: v_pk_fma_f32 (2 fp32 FMA/instr if CDNA4
// keeps packed fp32 at full rate). n-loop unrolled x2 for scalar-load ILP.

typedef float v2f __attribute__((ext_vector_type(2)));

constexpr int D       = 64;
constexpr int NW      = 65536;   // 256*256 weights
constexpr int B       = 4096;
constexpr int W_GRID  = 256;
constexpr int RB      = 16;      // row-blocks: 4096 rows / 256 rows-per-block

__global__ __launch_bounds__(256) void w2_kernel(const float* __restrict__ w,
                                                 float* __restrict__ w2) {
    int n = blockIdx.x * 256 + threadIdx.x;
    const float4* wr = reinterpret_cast<const float4*>(w + (size_t)n * D);
    float a0 = 0.f, a1 = 0.f, a2 = 0.f, a3 = 0.f;
#pragma unroll
    for (int q = 0; q < D / 4; ++q) {
        float4 v = wr[q];
        a0 = fmaf(v.x, v.x, a0);
        a1 = fmaf(v.y, v.y, a1);
        a2 = fmaf(v.z, v.z, a2);
        a3 = fmaf(v.w, v.w, a3);
    }
    w2[n] = (a0 + a1) + (a2 + a3);
}

template <int STRIPS>
__global__ __launch_bounds__(256) void som_main(const float* __restrict__ x,
                                                const float* __restrict__ w,
                                                const float* __restrict__ w2,
                                                float* __restrict__ ps,
                                                int* __restrict__ pi) {
    constexpr int NSTRIP = NW / STRIPS;
    const int rb    = blockIdx.x & (RB - 1);
    const int strip = blockIdx.x >> 4;
    const int row   = rb * 256 + threadIdx.x;

    // x row, pre-scaled by -2, pinned in 32 VGPR pairs.
    v2f xv[D / 2];
    const v2f* xrow = reinterpret_cast<const v2f*>(x + (size_t)row * D);
#pragma unroll
    for (int j = 0; j < D / 2; ++j) {
        v2f t = xrow[j];
        t = t * -2.0f;
        asm volatile("" : "+v"(t));   // forbid reload/remat: keep in VGPRs
        xv[j] = t;
    }

    float best = 3.4e38f;
    int   bidx = 0;
    const int n0 = strip * NSTRIP;
    const int n1 = n0 + NSTRIP;
    for (int n = n0; n < n1; n += 2) {
        const v2f* wv0 = reinterpret_cast<const v2f*>(w + (size_t)n * D);
        const v2f* wv1 = wv0 + D / 2;
        v2f a0 = {w2[n], 0.f},     a1 = {0.f, 0.f}, a2 = {0.f, 0.f}, a3 = {0.f, 0.f};
        v2f b0 = {w2[n + 1], 0.f}, b1 = {0.f, 0.f}, b2 = {0.f, 0.f}, b3 = {0.f, 0.f};
#pragma unroll
        for (int j = 0; j < 8; ++j) {
            a0 = __builtin_elementwise_fma(xv[4 * j + 0], wv0[4 * j + 0], a0);
            a1 = __builtin_elementwise_fma(xv[4 * j + 1], wv0[4 * j + 1], a1);
            a2 = __builtin_elementwise_fma(xv[4 * j + 2], wv0[4 * j + 2], a2);
            a3 = __builtin_elementwise_fma(xv[4 * j + 3], wv0[4 * j + 3], a3);
        }
#pragma unroll
        for (int j = 0; j < 8; ++j) {
            b0 = __builtin_elementwise_fma(xv[4 * j + 0], wv1[4 * j + 0], b0);
            b1 = __builtin_elementwise_fma(xv[4 * j + 1], wv1[4 * j + 1], b1);
            b2 = __builtin_elementwise_fma(xv[4 * j + 2], wv1[4 * j + 2], b2);
            b3 = __builtin_elementwise_fma(xv[4 * j + 3], wv1[4 * j + 3], b3);
        }
        float s0 = ((a0.x + a0.y) + (a1.x + a1.y)) + ((a2.x + a2.y) + (a3.x + a3.y));
        float s1 = ((b0.x + b0.y) + (b1.x + b1.y)) + ((b2.x + b2.y) + (b3.x + b3.y));
        // ascending n + strict < == first-occurrence argmin (matches jnp)
        bool c0 = s0 < best; best = c0 ? s0 : best; bidx = c0 ? n : bidx;
        bool c1 = s1 < best; best = c1 ? s1 : best; bidx = c1 ? n + 1 : bidx;
    }
    ps[(size_t)strip * B + row] = best;
    pi[(size_t)strip * B + row] = bidx;
}

template <int STRIPS>
__global__ __launch_bounds__(256) void som_merge(const float* __restrict__ x,
                                                 const float* __restrict__ ps,
                                                 const int* __restrict__ pi,
                                                 float* __restrict__ out) {
    int row = blockIdx.x * 256 + threadIdx.x;
    float bs = 3.5e38f;
    int   bi = 0;
    // strips visited in ascending-n order; tie -> smaller index wins
    for (int t = 0; t < STRIPS; ++t) {
        float s = ps[(size_t)t * B + row];
        int   i = pi[(size_t)t * B + row];
        if (s < bs || (s == bs && i < bi)) { bs = s; bi = i; }
    }
    const float4* xrow = reinterpret_cast<const float4*>(x + (size_t)row * D);
    float a0 = 0.f, a1 = 0.f, a2 = 0.f, a3 = 0.f;
#pragma unroll
    for (int q = 0; q < D / 4; ++q) {
        float4 v = xrow[q];
        a0 = fmaf(v.x, v.x, a0);
        a1 = fmaf(v.y, v.y, a1);
        a2 = fmaf(v.z, v.z, a2);
        a3 = fmaf(v.w, v.w, a3);
    }
    float x2 = (a0 + a1) + (a2 + a3);
    float d2 = x2 + bs;
    d2 = d2 < 0.f ? 0.f : d2;
    out[row * 2 + 0] = (float)(bi >> 8);           // bmu_y = n / 256
    out[row * 2 + 1] = (float)(bi & (W_GRID - 1)); // bmu_x = n % 256
    out[2 * B + row] = sqrtf(d2);
}

extern "C" void kernel_launch(void* const* d_in, const int* in_sizes, int n_in,
                              void* d_out, int out_size, void* d_ws, size_t ws_size,
                              hipStream_t stream) {
    const float* x = (const float*)d_in[0];   // [B, D]
    const float* w = (const float*)d_in[1];   // [NW, D]
    float* out = (float*)d_out;               // [B*2 + B] floats

    // workspace: w2[NW] | ps[STRIPS*B] | pi[STRIPS*B]
    float* w2 = (float*)d_ws;

    w2_kernel<<<NW / 256, 256, 0, stream>>>(w, w2);

    constexpr size_t need64 = (size_t)NW * 4 + (size_t)64 * B * 8;
    if (ws_size >= need64) {
        constexpr int S = 64;  // 1024 blocks -> 16 waves/CU
        float* ps = w2 + NW;
        int*   pi = (int*)(ps + (size_t)S * B);
        som_main<S><<<RB * S, 256, 0, stream>>>(x, w, w2, ps, pi);
        som_merge<S><<<B / 256, 256, 0, stream>>>(x, ps, pi, out);
    } else {
        constexpr int S = 32;
        float* ps = w2 + NW;
        int*   pi = (int*)(ps + (size_t)S * B);
        som_main<S><<<RB * S, 256, 0, stream>>>(x, w, w2, ps, pi);
        som_merge<S><<<B / 256, 256, 0, stream>>>(x, ps, pi, out);
    }
}

// Round 3
// 598.797 us; speedup vs baseline: 2.4974x; 1.2069x over previous
//
#include <hip/hip_runtime.h>
#include <math.h>

// SOM2dLayer forward: BMU indices + quantization error.
// X[4096,64] f32, W[256*256,64] f32.
// out (float32): [B*2] interleaved (y,x) as floats, then [B] qe.
//
// d2' = w2[n] - 2*x.w (x2 added back in merge). One batch row per thread.
// Round-1/2 failure: compiler re-loaded x inside the n-loop (VGPR=44) because
// load results are rematerializable. Fix: pass every x element through an
// opaque v_mov_b32 asm (asm results CANNOT be rematerialized -> must stay in
// VGPRs) + amdgpu_waves_per_eu(2) to raise the VGPR cap to 256.
// Inner loop: 32 v_pk_fma_f32 with x in VGPRs, wave-uniform w row in SGPRs.

typedef float v2f __attribute__((ext_vector_type(2)));

constexpr int D       = 64;
constexpr int NW      = 65536;   // 256*256 weights
constexpr int B       = 4096;
constexpr int W_GRID  = 256;
constexpr int RB      = 16;      // row-blocks: 4096 rows / 256 rows-per-block

__global__ __launch_bounds__(256) void w2_kernel(const float* __restrict__ w,
                                                 float* __restrict__ w2) {
    int n = blockIdx.x * 256 + threadIdx.x;
    const float4* wr = reinterpret_cast<const float4*>(w + (size_t)n * D);
    float a0 = 0.f, a1 = 0.f, a2 = 0.f, a3 = 0.f;
#pragma unroll
    for (int q = 0; q < D / 4; ++q) {
        float4 v = wr[q];
        a0 = fmaf(v.x, v.x, a0);
        a1 = fmaf(v.y, v.y, a1);
        a2 = fmaf(v.z, v.z, a2);
        a3 = fmaf(v.w, v.w, a3);
    }
    w2[n] = (a0 + a1) + (a2 + a3);
}

template <int STRIPS>
__global__ __launch_bounds__(256)
__attribute__((amdgpu_waves_per_eu(2)))            // VGPR cap 256: no pressure excuse
void som_main(const float* __restrict__ x,
              const float* __restrict__ w,
              const float* __restrict__ w2,
              float* __restrict__ ps,
              int* __restrict__ pi) {
    constexpr int NSTRIP = NW / STRIPS;
    const int rb    = blockIdx.x & (RB - 1);
    const int strip = blockIdx.x >> 4;
    const int row   = rb * 256 + threadIdx.x;

    // x row, pre-scaled by -2, forced into VGPRs: each element is the result
    // of an opaque v_mov_b32 -> not rematerializable by reloading.
    v2f xv[D / 2];
    const v2f* xrow = reinterpret_cast<const v2f*>(x + (size_t)row * D);
#pragma unroll
    for (int j = 0; j < D / 2; ++j) {
        v2f t = xrow[j];
        t = t * -2.0f;
        float a, b;
        asm("v_mov_b32 %0, %2\n\t"
            "v_mov_b32 %1, %3"
            : "=v"(a), "=v"(b)
            : "v"(t.x), "v"(t.y));
        v2f p; p.x = a; p.y = b;
        xv[j] = p;
    }

    float best = 3.4e38f;
    int   bidx = 0;
    const int n0 = strip * NSTRIP;
    const int n1 = n0 + NSTRIP;
    for (int n = n0; n < n1; n += 2) {
        const v2f* wv0 = reinterpret_cast<const v2f*>(w + (size_t)n * D);  // wave-uniform -> s_load
        const v2f* wv1 = wv0 + D / 2;
        v2f a0 = {0.f, 0.f}, a1 = {0.f, 0.f}, a2 = {0.f, 0.f}, a3 = {0.f, 0.f};
        v2f b0 = {0.f, 0.f}, b1 = {0.f, 0.f}, b2 = {0.f, 0.f}, b3 = {0.f, 0.f};
#pragma unroll
        for (int j = 0; j < 8; ++j) {
            a0 = __builtin_elementwise_fma(xv[4 * j + 0], wv0[4 * j + 0], a0);
            a1 = __builtin_elementwise_fma(xv[4 * j + 1], wv0[4 * j + 1], a1);
            a2 = __builtin_elementwise_fma(xv[4 * j + 2], wv0[4 * j + 2], a2);
            a3 = __builtin_elementwise_fma(xv[4 * j + 3], wv0[4 * j + 3], a3);
        }
#pragma unroll
        for (int j = 0; j < 8; ++j) {
            b0 = __builtin_elementwise_fma(xv[4 * j + 0], wv1[4 * j + 0], b0);
            b1 = __builtin_elementwise_fma(xv[4 * j + 1], wv1[4 * j + 1], b1);
            b2 = __builtin_elementwise_fma(xv[4 * j + 2], wv1[4 * j + 2], b2);
            b3 = __builtin_elementwise_fma(xv[4 * j + 3], wv1[4 * j + 3], b3);
        }
        v2f ra = (a0 + a1) + (a2 + a3);
        v2f rb2 = (b0 + b1) + (b2 + b3);
        float s0 = (ra.x + ra.y) + w2[n];
        float s1 = (rb2.x + rb2.y) + w2[n + 1];
        // ascending n + strict < == first-occurrence argmin (matches jnp)
        bool c0 = s0 < best; best = c0 ? s0 : best; bidx = c0 ? n : bidx;
        bool c1 = s1 < best; best = c1 ? s1 : best; bidx = c1 ? n + 1 : bidx;
    }
    ps[(size_t)strip * B + row] = best;
    pi[(size_t)strip * B + row] = bidx;
}

template <int STRIPS>
__global__ __launch_bounds__(256) void som_merge(const float* __restrict__ x,
                                                 const float* __restrict__ ps,
                                                 const int* __restrict__ pi,
                                                 float* __restrict__ out) {
    int row = blockIdx.x * 256 + threadIdx.x;
    float bs = 3.5e38f;
    int   bi = 0;
    // strips visited in ascending-n order; tie -> smaller index wins
    for (int t = 0; t < STRIPS; ++t) {
        float s = ps[(size_t)t * B + row];
        int   i = pi[(size_t)t * B + row];
        if (s < bs || (s == bs && i < bi)) { bs = s; bi = i; }
    }
    const float4* xrow = reinterpret_cast<const float4*>(x + (size_t)row * D);
    float a0 = 0.f, a1 = 0.f, a2 = 0.f, a3 = 0.f;
#pragma unroll
    for (int q = 0; q < D / 4; ++q) {
        float4 v = xrow[q];
        a0 = fmaf(v.x, v.x, a0);
        a1 = fmaf(v.y, v.y, a1);
        a2 = fmaf(v.z, v.z, a2);
        a3 = fmaf(v.w, v.w, a3);
    }
    float x2 = (a0 + a1) + (a2 + a3);
    float d2 = x2 + bs;
    d2 = d2 < 0.f ? 0.f : d2;
    out[row * 2 + 0] = (float)(bi >> 8);           // bmu_y = n / 256
    out[row * 2 + 1] = (float)(bi & (W_GRID - 1)); // bmu_x = n % 256
    out[2 * B + row] = sqrtf(d2);
}

extern "C" void kernel_launch(void* const* d_in, const int* in_sizes, int n_in,
                              void* d_out, int out_size, void* d_ws, size_t ws_size,
                              hipStream_t stream) {
    const float* x = (const float*)d_in[0];   // [B, D]
    const float* w = (const float*)d_in[1];   // [NW, D]
    float* out = (float*)d_out;               // [B*2 + B] floats

    // workspace: w2[NW] | ps[STRIPS*B] | pi[STRIPS*B]
    float* w2 = (float*)d_ws;

    w2_kernel<<<NW / 256, 256, 0, stream>>>(w, w2);

    constexpr size_t need64 = (size_t)NW * 4 + (size_t)64 * B * 8;
    if (ws_size >= need64) {
        constexpr int S = 64;  // 1024 blocks -> 4 blocks/CU, 4 waves/SIMD
        float* ps = w2 + NW;
        int*   pi = (int*)(ps + (size_t)S * B);
        som_main<S><<<RB * S, 256, 0, stream>>>(x, w, w2, ps, pi);
        som_merge<S><<<B / 256, 256, 0, stream>>>(x, ps, pi, out);
    } else {
        constexpr int S = 32;
        float* ps = w2 + NW;
        int*   pi = (int*)(ps + (size_t)S * B);
        som_main<S><<<RB * S, 256, 0, stream>>>(x, w, w2, ps, pi);
        som_merge<S><<<B / 256, 256, 0, stream>>>(x, ps, pi, out);
    }
}

// Round 4
// 201.157 us; speedup vs baseline: 7.4343x; 2.9768x over previous
//
#include <hip/hip_runtime.h>
#include <math.h>

// SOM2dLayer forward: BMU indices + quantization error via bf16-MFMA screen
// + exact fp32 rescore.
// X[4096,64] f32, W[65536,64] f32 -> out f32: [B*2] (y,x) then [B] qe.
//
// s(row,n) = w2[n] - 2*x.w  (x2 added only for qe). Phases:
//   prep:   w_hi = bf16(w), w2c = -0.5*sum(w^2); x_hi = bf16(x)
//   screen0: per (panel,row) max of acc' where acc' = dot_bf16 - w2/2
//            (min of s  <=>  max of acc', since s = -2*acc')
//   reduce: thr2[row] = global max - MARGIN/2 ; cnt = 0
//   screen1: same MFMA recompute; collect n where acc' >= thr2 (atomic append)
//   final:  exact fp32 rescore of <=64 candidates/row, argmin w/ index
//           tie-break (matches np first-occurrence), qe = sqrt(max(x2+s,0))

typedef short  bf16x8 __attribute__((ext_vector_type(8)));
typedef float  f32x4  __attribute__((ext_vector_type(4)));
typedef unsigned short u16;

constexpr int D        = 64;
constexpr int NW       = 65536;
constexpr int B        = 4096;
constexpr int NPANELS  = 256;        // panels of 256 n
constexpr int CAND_CAP = 64;
constexpr float MARG_HALF = 0.15f;   // margin 0.3 in distance space

__device__ inline u16 bf16u(float f) {
    union { float f; unsigned u; } v; v.f = f;
    unsigned b = v.u;
    b += 0x7fffu + ((b >> 16) & 1u);   // RNE, finite inputs only
    return (u16)(b >> 16);
}

// ---- prep: W -> bf16 + w2c ------------------------------------------------
__global__ __launch_bounds__(256) void k_wprep(const float* __restrict__ w,
                                               u16* __restrict__ whi,
                                               float* __restrict__ w2c) {
    int n = blockIdx.x * 256 + threadIdx.x;
    const float4* wr = reinterpret_cast<const float4*>(w + (size_t)n * D);
    u16* orow = whi + (size_t)n * D;
    float a0 = 0.f, a1 = 0.f, a2 = 0.f, a3 = 0.f;
#pragma unroll
    for (int h = 0; h < 8; ++h) {
        float4 v0 = wr[2 * h], v1 = wr[2 * h + 1];
        a0 = fmaf(v0.x, v0.x, a0); a1 = fmaf(v0.y, v0.y, a1);
        a2 = fmaf(v0.z, v0.z, a2); a3 = fmaf(v0.w, v0.w, a3);
        a0 = fmaf(v1.x, v1.x, a0); a1 = fmaf(v1.y, v1.y, a1);
        a2 = fmaf(v1.z, v1.z, a2); a3 = fmaf(v1.w, v1.w, a3);
        bf16x8 o = {(short)bf16u(v0.x), (short)bf16u(v0.y),
                    (short)bf16u(v0.z), (short)bf16u(v0.w),
                    (short)bf16u(v1.x), (short)bf16u(v1.y),
                    (short)bf16u(v1.z), (short)bf16u(v1.w)};
        *reinterpret_cast<bf16x8*>(orow + 8 * h) = o;
    }
    w2c[n] = -0.5f * ((a0 + a1) + (a2 + a3));
}

__global__ __launch_bounds__(256) void k_xprep(const float* __restrict__ x,
                                               u16* __restrict__ xhi) {
    int r = blockIdx.x * 256 + threadIdx.x;
    const float4* xr = reinterpret_cast<const float4*>(x + (size_t)r * D);
    u16* orow = xhi + (size_t)r * D;
#pragma unroll
    for (int h = 0; h < 8; ++h) {
        float4 v0 = xr[2 * h], v1 = xr[2 * h + 1];
        bf16x8 o = {(short)bf16u(v0.x), (short)bf16u(v0.y),
                    (short)bf16u(v0.z), (short)bf16u(v0.w),
                    (short)bf16u(v1.x), (short)bf16u(v1.y),
                    (short)bf16u(v1.z), (short)bf16u(v1.w)};
        *reinterpret_cast<bf16x8*>(orow + 8 * h) = o;
    }
}

// ---- MFMA screen (PHASE 0: per-panel max; PHASE 1: collect candidates) ----
// Wave covers 128 rows (8 groups of 16) x 256-n panel (16 tiles).
// Block = 4 waves = 512 rows. Grid = 8 row-blocks * 256 panels = 2048.
template <int PHASE>
__global__ __launch_bounds__(256, 1) void k_screen(const u16* __restrict__ whi,
                                                   const u16* __restrict__ xhi,
                                                   const float* __restrict__ w2c,
                                                   float* __restrict__ pm,
                                                   const float* __restrict__ thr2,
                                                   int* __restrict__ cnt,
                                                   int* __restrict__ cand) {
    const int rb   = blockIdx.x & 7;
    const int pb   = blockIdx.x >> 3;
    const int wave = threadIdx.x >> 6;
    const int lane = threadIdx.x & 63;
    const int col  = lane & 15;        // MFMA M/N lane index
    const int kg   = lane >> 4;        // k-group 0..3
    const int row0 = rb * 512 + wave * 128;
    const int p0   = pb * 256;

    // A fragments: 8 row-groups x 2 k-halves, each 8 contiguous bf16 (16B).
    bf16x8 a[8][2];
#pragma unroll
    for (int g = 0; g < 8; ++g)
#pragma unroll
        for (int h = 0; h < 2; ++h)
            a[g][h] = *reinterpret_cast<const bf16x8*>(
                xhi + (size_t)(row0 + g * 16 + col) * D + h * 32 + kg * 8);

    float m[8][4];
    float t[8][4];
    if (PHASE == 0) {
#pragma unroll
        for (int g = 0; g < 8; ++g)
#pragma unroll
            for (int r = 0; r < 4; ++r) m[g][r] = -3.4e38f;
    } else {
#pragma unroll
        for (int g = 0; g < 8; ++g)
#pragma unroll
            for (int r = 0; r < 4; ++r)
                t[g][r] = thr2[row0 + g * 16 + kg * 4 + r];
    }

    for (int tl = 0; tl < 16; ++tl) {
        const int n = p0 + tl * 16 + col;
        const bf16x8 b0 = *reinterpret_cast<const bf16x8*>(whi + (size_t)n * D + kg * 8);
        const bf16x8 b1 = *reinterpret_cast<const bf16x8*>(whi + (size_t)n * D + 32 + kg * 8);
        const float c = w2c[n];
        f32x4 acc[8];
#pragma unroll
        for (int g = 0; g < 8; ++g) acc[g] = (f32x4){c, c, c, c};
#pragma unroll
        for (int g = 0; g < 8; ++g)
            acc[g] = __builtin_amdgcn_mfma_f32_16x16x32_bf16(a[g][0], b0, acc[g], 0, 0, 0);
#pragma unroll
        for (int g = 0; g < 8; ++g)
            acc[g] = __builtin_amdgcn_mfma_f32_16x16x32_bf16(a[g][1], b1, acc[g], 0, 0, 0);

        if (PHASE == 0) {
#pragma unroll
            for (int g = 0; g < 8; ++g)
#pragma unroll
                for (int r = 0; r < 4; ++r) m[g][r] = fmaxf(m[g][r], acc[g][r]);
        } else {
            float dg[8];
#pragma unroll
            for (int g = 0; g < 8; ++g)
                dg[g] = fmaxf(fmaxf(acc[g][0] - t[g][0], acc[g][1] - t[g][1]),
                              fmaxf(acc[g][2] - t[g][2], acc[g][3] - t[g][3]));
            float dm = fmaxf(fmaxf(fmaxf(dg[0], dg[1]), fmaxf(dg[2], dg[3])),
                             fmaxf(fmaxf(dg[4], dg[5]), fmaxf(dg[6], dg[7])));
            if (__any(dm >= 0.f)) {   // rare slow path
#pragma unroll
                for (int g = 0; g < 8; ++g)
#pragma unroll
                    for (int r = 0; r < 4; ++r)
                        if (acc[g][r] >= t[g][r]) {
                            int row  = row0 + g * 16 + kg * 4 + r;
                            int slot = atomicAdd(&cnt[row], 1);
                            if (slot < CAND_CAP) cand[row * CAND_CAP + slot] = n;
                        }
            }
        }
    }

    if (PHASE == 0) {
        // fold the 16 cols (lanes sharing kg) -> per-row panel max
#pragma unroll
        for (int g = 0; g < 8; ++g)
#pragma unroll
            for (int r = 0; r < 4; ++r) {
                float v = m[g][r];
                v = fmaxf(v, __shfl_xor(v, 1, 64));
                v = fmaxf(v, __shfl_xor(v, 2, 64));
                v = fmaxf(v, __shfl_xor(v, 4, 64));
                v = fmaxf(v, __shfl_xor(v, 8, 64));
                m[g][r] = v;
            }
        if (col == 0) {
#pragma unroll
            for (int g = 0; g < 8; ++g)
#pragma unroll
                for (int r = 0; r < 4; ++r)
                    pm[(size_t)pb * B + row0 + g * 16 + kg * 4 + r] = m[g][r];
        }
    }
}

// ---- reduce panel maxima -> threshold; zero candidate counters ------------
__global__ __launch_bounds__(256) void k_reduce(const float* __restrict__ pm,
                                                float* __restrict__ thr2,
                                                int* __restrict__ cnt) {
    int row = blockIdx.x * 256 + threadIdx.x;
    float gm = -3.4e38f;
    for (int p = 0; p < NPANELS; ++p) gm = fmaxf(gm, pm[(size_t)p * B + row]);
    thr2[row] = gm - MARG_HALF;
    cnt[row] = 0;
}

// ---- exact fp32 rescore + output ------------------------------------------
__global__ __launch_bounds__(256) void k_final(const float* __restrict__ x,
                                               const float* __restrict__ w,
                                               const float* __restrict__ w2c,
                                               const int* __restrict__ cnt,
                                               const int* __restrict__ cand,
                                               float* __restrict__ out) {
    int row  = blockIdx.x * 4 + (threadIdx.x >> 6);
    int lane = threadIdx.x & 63;
    int c = cnt[row]; c = c < CAND_CAP ? c : CAND_CAP;
    float val = 3.4e38f;
    int   ni  = 0x7fffffff;
    if (lane < c) {
        int n = cand[row * CAND_CAP + lane];
        const float4* wr = reinterpret_cast<const float4*>(w + (size_t)n * D);
        const float4* xr = reinterpret_cast<const float4*>(x + (size_t)row * D);
        float d0 = 0.f, d1 = 0.f, d2 = 0.f, d3 = 0.f;
#pragma unroll
        for (int q = 0; q < 16; ++q) {
            float4 wv = wr[q];
            float4 xv = xr[q];
            d0 = fmaf(xv.x, wv.x, d0); d1 = fmaf(xv.y, wv.y, d1);
            d2 = fmaf(xv.z, wv.z, d2); d3 = fmaf(xv.w, wv.w, d3);
        }
        float dot = (d0 + d1) + (d2 + d3);
        val = -2.f * (dot + w2c[n]);      // == w2 - 2*x.w
        ni  = n;
    }
#pragma unroll
    for (int s = 1; s < 64; s <<= 1) {
        float ov = __shfl_xor(val, s, 64);
        int   oi = __shfl_xor(ni, s, 64);
        if (ov < val || (ov == val && oi < ni)) { val = ov; ni = oi; }
    }
    if (lane == 0) {
        const float4* xr = reinterpret_cast<const float4*>(x + (size_t)row * D);
        float a0 = 0.f, a1 = 0.f, a2 = 0.f, a3 = 0.f;
#pragma unroll
        for (int q = 0; q < 16; ++q) {
            float4 v = xr[q];
            a0 = fmaf(v.x, v.x, a0); a1 = fmaf(v.y, v.y, a1);
            a2 = fmaf(v.z, v.z, a2); a3 = fmaf(v.w, v.w, a3);
        }
        float x2 = (a0 + a1) + (a2 + a3);
        float d2f = x2 + val;
        if (d2f < 0.f) d2f = 0.f;
        out[row * 2 + 0] = (float)(ni >> 8);    // bmu_y
        out[row * 2 + 1] = (float)(ni & 255);   // bmu_x
        out[2 * B + row] = sqrtf(d2f);
    }
}

// ---- fallback (round-3 proven path, needs only ~1.3 MB ws) ----------------
__global__ __launch_bounds__(256) void fb_w2(const float* __restrict__ w,
                                             float* __restrict__ w2) {
    int n = blockIdx.x * 256 + threadIdx.x;
    const float4* wr = reinterpret_cast<const float4*>(w + (size_t)n * D);
    float a0 = 0.f, a1 = 0.f, a2 = 0.f, a3 = 0.f;
#pragma unroll
    for (int q = 0; q < 16; ++q) {
        float4 v = wr[q];
        a0 = fmaf(v.x, v.x, a0); a1 = fmaf(v.y, v.y, a1);
        a2 = fmaf(v.z, v.z, a2); a3 = fmaf(v.w, v.w, a3);
    }
    w2[n] = (a0 + a1) + (a2 + a3);
}

__global__ __launch_bounds__(256) void fb_main(const float* __restrict__ x,
                                               const float* __restrict__ w,
                                               const float* __restrict__ w2,
                                               float* __restrict__ ps,
                                               int* __restrict__ pi) {
    constexpr int NSTRIP = NW / 32;
    const int rb    = blockIdx.x & 15;
    const int strip = blockIdx.x >> 4;
    const int row   = rb * 256 + threadIdx.x;
    float xr[D];
    const float4* xrow = reinterpret_cast<const float4*>(x + (size_t)row * D);
#pragma unroll
    for (int q = 0; q < 16; ++q) {
        float4 v = xrow[q];
        xr[q * 4 + 0] = v.x; xr[q * 4 + 1] = v.y;
        xr[q * 4 + 2] = v.z; xr[q * 4 + 3] = v.w;
    }
    float best = 3.4e38f; int bidx = 0;
    const int n0 = strip * NSTRIP, n1 = n0 + NSTRIP;
    for (int n = n0; n < n1; ++n) {
        const float* wr = w + (size_t)n * D;
        float a0 = 0.f, a1 = 0.f, a2 = 0.f, a3 = 0.f;
#pragma unroll
        for (int d = 0; d < D; d += 4) {
            a0 = fmaf(xr[d + 0], wr[d + 0], a0);
            a1 = fmaf(xr[d + 1], wr[d + 1], a1);
            a2 = fmaf(xr[d + 2], wr[d + 2], a2);
            a3 = fmaf(xr[d + 3], wr[d + 3], a3);
        }
        float s = fmaf(-2.f, (a0 + a1) + (a2 + a3), w2[n]);
        if (s < best) { best = s; bidx = n; }
    }
    ps[(size_t)strip * B + row] = best;
    pi[(size_t)strip * B + row] = bidx;
}

__global__ __launch_bounds__(256) void fb_merge(const float* __restrict__ x,
                                                const float* __restrict__ ps,
                                                const int* __restrict__ pi,
                                                float* __restrict__ out) {
    int row = blockIdx.x * 256 + threadIdx.x;
    float bs = 3.5e38f; int bi = 0;
    for (int t = 0; t < 32; ++t) {
        float s = ps[(size_t)t * B + row];
        int   i = pi[(size_t)t * B + row];
        if (s < bs || (s == bs && i < bi)) { bs = s; bi = i; }
    }
    const float4* xrow = reinterpret_cast<const float4*>(x + (size_t)row * D);
    float a0 = 0.f, a1 = 0.f, a2 = 0.f, a3 = 0.f;
#pragma unroll
    for (int q = 0; q < 16; ++q) {
        float4 v = xrow[q];
        a0 = fmaf(v.x, v.x, a0); a1 = fmaf(v.y, v.y, a1);
        a2 = fmaf(v.z, v.z, a2); a3 = fmaf(v.w, v.w, a3);
    }
    float x2 = (a0 + a1) + (a2 + a3);
    float d2 = x2 + bs;
    if (d2 < 0.f) d2 = 0.f;
    out[row * 2 + 0] = (float)(bi >> 8);
    out[row * 2 + 1] = (float)(bi & 255);
    out[2 * B + row] = sqrtf(d2);
}

// ---------------------------------------------------------------------------
extern "C" void kernel_launch(void* const* d_in, const int* in_sizes, int n_in,
                              void* d_out, int out_size, void* d_ws, size_t ws_size,
                              hipStream_t stream) {
    const float* x = (const float*)d_in[0];   // [B, D]
    const float* w = (const float*)d_in[1];   // [NW, D]
    float* out = (float*)d_out;

    const size_t whi_sz  = (size_t)NW * D * 2;
    const size_t xhi_sz  = (size_t)B * D * 2;
    const size_t w2c_sz  = (size_t)NW * 4;
    const size_t pm_sz   = (size_t)NPANELS * B * 4;
    const size_t thr_sz  = (size_t)B * 4;
    const size_t cnt_sz  = (size_t)B * 4;
    const size_t cand_sz = (size_t)B * CAND_CAP * 4;
    const size_t need = whi_sz + xhi_sz + w2c_sz + pm_sz + thr_sz + cnt_sz + cand_sz;

    if (ws_size >= need) {
        char* p = (char*)d_ws;
        u16*   whi  = (u16*)p;            p += whi_sz;
        u16*   xhi  = (u16*)p;            p += xhi_sz;
        float* w2c  = (float*)p;          p += w2c_sz;
        float* pm   = (float*)p;          p += pm_sz;
        float* thr2 = (float*)p;          p += thr_sz;
        int*   cnt  = (int*)p;            p += cnt_sz;
        int*   cand = (int*)p;

        k_wprep<<<NW / 256, 256, 0, stream>>>(w, whi, w2c);
        k_xprep<<<B / 256, 256, 0, stream>>>(x, xhi);
        k_screen<0><<<2048, 256, 0, stream>>>(whi, xhi, w2c, pm, thr2, cnt, cand);
        k_reduce<<<B / 256, 256, 0, stream>>>(pm, thr2, cnt);
        k_screen<1><<<2048, 256, 0, stream>>>(whi, xhi, w2c, pm, thr2, cnt, cand);
        k_final<<<B / 4, 256, 0, stream>>>(x, w, w2c, cnt, cand, out);
    } else {
        float* w2 = (float*)d_ws;
        float* ps = w2 + NW;
        int*   pi = (int*)(ps + (size_t)32 * B);
        fb_w2<<<NW / 256, 256, 0, stream>>>(w, w2);
        fb_main<<<16 * 32, 256, 0, stream>>>(x, w, w2, ps, pi);
        fb_merge<<<B / 256, 256, 0, stream>>>(x, ps, pi, out);
    }
}